// Round 2
// baseline (63.044 us; speedup 1.0000x reference)
//
#include <hip/hip_runtime.h>
#include <hip/hip_fp16.h>

// TensorFusion: out = tanh(tanh(tanh(fusion@W1+b1)@W2+b2)@W3+b3)
// fusion[b,(i,j,k)] = a_h[b,i]*v_h[b,j]*t_h[b,k], a_h=[1,a], 65^3 = 274625 cols.
// K decomposes into 4291 segments of K=64 (+ row 0 folded into tail bias):
// per segment, A[b,t] = scale[b]*inner[b,t] generated in-register; W1 seg tile
// (64 rows x 64 cols fp32) reg-staged -> cvt f16 -> LDS transposed (XOR-swizzled).
// Grid=256 (1 block/CU), 1024 thr (16 waves), BM=512 -> W1 read exactly once.
// Raw asm barrier keeps prefetch loads in flight (no vmcnt(0) drain).
// Split-K f16 partials [row][256][64] reduced in tail fused with the 64x64 MLP.

typedef _Float16 f16;
typedef f16 f16x8 __attribute__((ext_vector_type(8)));
typedef f16 f16x2 __attribute__((ext_vector_type(2)));
typedef float f32x4 __attribute__((ext_vector_type(4)));

#define WS_AT      0
#define WS_VT      131072
#define WS_A16     262144
#define WS_V16     327680
#define WS_L16     393216
#define WS_PART    458752   // f16 [512][256][64] = 16777216 B

// ---------------- prep: transposes + f16 casts ----------------
__global__ __launch_bounds__(256) void prep_kernel(
    const float* __restrict__ l, const float* __restrict__ a, const float* __restrict__ v,
    float* __restrict__ aT, float* __restrict__ vT,
    f16* __restrict__ a16, f16* __restrict__ v16, f16* __restrict__ l16)
{
  int g = blockIdx.x * 256 + threadIdx.x;   // 5*32768 items
  int which = g >> 15;
  int idx = g & 32767;
  switch (which) {
    case 0: aT[idx] = a[((idx & 511) << 6) + (idx >> 9)]; break;  // aT[c][r]=a[r][c]
    case 1: vT[idx] = v[((idx & 511) << 6) + (idx >> 9)]; break;
    case 2: a16[idx] = (f16)a[idx]; break;
    case 3: v16[idx] = (f16)v[idx]; break;
    case 4: l16[idx] = (f16)l[idx]; break;
  }
}

__device__ __forceinline__ void seg_decode(int s, int& ia, int& iv, int& isel,
                                           int& rowbase, int& rowstride) {
  if (s < 4096)      { int i = s >> 6, j = s & 63; ia = i; iv = j; isel = 0;
                       rowbase = (i+1)*4225 + (j+1)*65 + 1; rowstride = 1; }
  else if (s < 4160) { int i = s - 4096; ia = i; iv = -1; isel = 2;
                       rowbase = (i+1)*4225 + 65; rowstride = 65; }
  else if (s < 4224) { int i = s - 4160; ia = i; iv = -1; isel = 0;
                       rowbase = (i+1)*4225 + 1; rowstride = 1; }
  else if (s < 4288) { int j = s - 4224; ia = -1; iv = j; isel = 0;
                       rowbase = (j+1)*65 + 1; rowstride = 1; }
  else if (s == 4288){ ia = -1; iv = -1; isel = 1; rowbase = 4225; rowstride = 4225; }
  else if (s == 4289){ ia = -1; iv = -1; isel = 2; rowbase = 65;   rowstride = 65; }
  else if (s == 4290){ ia = -1; iv = -1; isel = 0; rowbase = 1;    rowstride = 1; }
  else               { ia = -2; iv = -1; isel = 0; rowbase = 1;    rowstride = 1; } // dummy: scale 0
}

// ---------------- stage 1: the big implicit GEMM ----------------
__global__ __launch_bounds__(1024, 4) void fusion_gemm(
    const float* __restrict__ W1,
    const float* __restrict__ aT, const float* __restrict__ vT,
    const f16* __restrict__ a16, const f16* __restrict__ v16, const f16* __restrict__ l16,
    f16* __restrict__ partials)
{
  __shared__ f16 btile[4][64 * 64];   // 4 seg-buffers, [n][k] f16, 16B chunks XOR-swizzled
  __shared__ f16 pl[4][512];          // per-row scale per seg-buffer

  const int tid  = threadIdx.x;
  const int bid  = blockIdx.x;
  const int lane = tid & 63;
  const int wave = tid >> 6;          // 0..15
  const int l15  = lane & 15;
  const int l4   = lane >> 4;
  const int h    = tid >> 9;          // staging half: seg (2pp+h)
  const int t9   = tid & 511;
  const int n_st = t9 & 63;           // staging: W1 col
  const int g_st = t9 >> 6;           // staging: k-group (8 rows)

  // A-fragments of l in registers (isel==0 path): 2 mt x 2 ks
  f16x8 lfrag[2][2];
  #pragma unroll
  for (int mt = 0; mt < 2; ++mt) {
    int row = (wave << 5) + (mt << 4) + l15;
    #pragma unroll
    for (int ks = 0; ks < 2; ++ks)
      lfrag[mt][ks] = *(const f16x8*)(l16 + (row << 6) + (ks << 5) + (l4 << 3));
  }

  f32x4 acc[2][4] = {};               // 32 VGPRs

  float wv[2][8];                     // staging double-buffer (static-indexed via full unroll)
  float sp[2][2];

#define ISSUE_LOADS(SET, SEG) do {                                              \
    int ia_, iv_, isel_, rb_, rs_; seg_decode((SEG), ia_, iv_, isel_, rb_, rs_);\
    const int rs64_ = rs_ << 6;                                                 \
    const float* src_ = W1 + (size_t)rb_ * 64 + (size_t)(g_st << 3) * rs64_ + n_st; \
    _Pragma("unroll")                                                           \
    for (int r_ = 0; r_ < 8; ++r_) wv[SET][r_] = src_[(size_t)r_ * rs64_];      \
    sp[SET][0] = (ia_ >= 0) ? aT[(ia_ << 9) + t9] : (ia_ == -1 ? 1.0f : 0.0f);  \
    sp[SET][1] = (iv_ >= 0) ? vT[(iv_ << 9) + t9] : 1.0f;                       \
  } while (0)

  ISSUE_LOADS(0, bid * 18 + h);

  #pragma unroll
  for (int pp = 0; pp < 9; ++pp) {
    const int cur = pp & 1;
    const int sbw = (cur << 1) + h;   // this half's write buffer
    { // cvt staged regs -> LDS (compiler waits the matching vmcnt here)
      f16x8 c;
      if (cur == 0) {
        #pragma unroll
        for (int r = 0; r < 8; ++r) c[r] = (f16)wv[0][r];
      } else {
        #pragma unroll
        for (int r = 0; r < 8; ++r) c[r] = (f16)wv[1][r];
      }
      *(f16x8*)&btile[sbw][(n_st << 6) + ((g_st ^ (n_st & 7)) << 3)] = c;
      pl[sbw][t9] = (f16)(sp[cur][0] * sp[cur][1]);
    }
    // prefetch next pair; these global loads stay in flight across the barrier
    if (pp < 8) {
      if (cur == 0) ISSUE_LOADS(1, bid * 18 + (pp + 1) * 2 + h);
      else          ISSUE_LOADS(0, bid * 18 + (pp + 1) * 2 + h);
    }
    // drain only LDS writes, then barrier (NOT __syncthreads: no vmcnt(0) drain)
    asm volatile("s_waitcnt lgkmcnt(0)\n\ts_barrier" ::: "memory");
    __builtin_amdgcn_sched_barrier(0);

    #pragma unroll
    for (int sidx = 0; sidx < 2; ++sidx) {
      const int sb = (cur << 1) + sidx;
      int s = bid * 18 + pp * 2 + sidx;
      int ia_, iv_, isel, rb_, rs_;
      seg_decode(s, ia_, iv_, isel, rb_, rs_);
      const f16* gsrc = (isel == 1) ? a16 : v16;
      #pragma unroll
      for (int ks = 0; ks < 2; ++ks) {
        f16x8 bf[4];
        #pragma unroll
        for (int nt = 0; nt < 4; ++nt) {
          int n = (nt << 4) + l15;
          bf[nt] = *(const f16x8*)&btile[sb][(n << 6) + ((((ks << 2) + l4) ^ (n & 7)) << 3)];
        }
        #pragma unroll
        for (int mt = 0; mt < 2; ++mt) {
          int row = (wave << 5) + (mt << 4) + l15;
          f16 ps = pl[sb][row];
          f16x8 lv;
          if (isel == 0) lv = lfrag[mt][ks];
          else           lv = *(const f16x8*)(gsrc + (row << 6) + (ks << 5) + (l4 << 3));
          f16x2 ps2 = { ps, ps };
          f16x8 av;
          f16x2* lvp = (f16x2*)&lv;
          f16x2* avp = (f16x2*)&av;
          avp[0] = lvp[0] * ps2; avp[1] = lvp[1] * ps2;
          avp[2] = lvp[2] * ps2; avp[3] = lvp[3] * ps2;
          #pragma unroll
          for (int nt = 0; nt < 4; ++nt)
            acc[mt][nt] = __builtin_amdgcn_mfma_f32_16x16x32_f16(av, bf[nt], acc[mt][nt], 0, 0, 0);
        }
      }
    }
  }
#undef ISSUE_LOADS

  // epilogue: f16 partials, layout [row][p=bid][n] -> tail reads contiguous per row
  #pragma unroll
  for (int mt = 0; mt < 2; ++mt)
    #pragma unroll
    for (int nt = 0; nt < 4; ++nt)
      #pragma unroll
      for (int r = 0; r < 4; ++r) {
        int row = (wave << 5) + (mt << 4) + (l4 << 2) + r;
        int col = (nt << 4) + l15;
        partials[((size_t)row << 14) + (bid << 6) + col] = (f16)acc[mt][nt][r];
      }
}

// ---------------- tail: reduce partials + bias + tanh + 2x 64x64 GEMM ----------------
__global__ __launch_bounds__(256) void tail_kernel(
    const f16* __restrict__ partials, const float* __restrict__ W1, const float* __restrict__ b1,
    const float* __restrict__ W2, const float* __restrict__ b2,
    const float* __restrict__ W3, const float* __restrict__ b3, float* __restrict__ out)
{
  __shared__ float red[256][8];
  __shared__ float hbuf[64];
  __shared__ float h2buf[64];
  const int row = blockIdx.x;          // 0..511
  const int t = threadIdx.x;
  const f16* base = partials + ((size_t)row << 14);  // 16384 f16, contiguous

  float s[8] = {0.f,0.f,0.f,0.f,0.f,0.f,0.f,0.f};
  #pragma unroll
  for (int j = 0; j < 8; ++j) {
    f16x8 v = *(const f16x8*)(base + (((j << 8) + t) << 3));
    #pragma unroll
    for (int e = 0; e < 8; ++e) s[e] += (float)v[e];
  }
  #pragma unroll
  for (int e = 0; e < 8; ++e) red[t][e] = s[e];
  __syncthreads();
  if (t < 64) {
    float acc = b1[t] + W1[t];         // + row-0 (1*1*1) term
    #pragma unroll
    for (int k = 0; k < 32; ++k) acc += red[(t >> 3) + (k << 3)][t & 7];
    hbuf[t] = tanhf(acc);
  }
  __syncthreads();
  if (t < 64) {
    float acc = b2[t];
    #pragma unroll 8
    for (int k = 0; k < 64; ++k) acc += hbuf[k] * W2[(k << 6) + t];
    h2buf[t] = tanhf(acc);
  }
  __syncthreads();
  if (t < 64) {
    float acc = b3[t];
    #pragma unroll 8
    for (int k = 0; k < 64; ++k) acc += h2buf[k] * W3[(k << 6) + t];
    out[(row << 6) + t] = tanhf(acc);
  }
}

extern "C" void kernel_launch(void* const* d_in, const int* in_sizes, int n_in,
                              void* d_out, int out_size, void* d_ws, size_t ws_size,
                              hipStream_t stream) {
  const float* l  = (const float*)d_in[0];
  const float* a  = (const float*)d_in[1];
  const float* v  = (const float*)d_in[2];
  const float* W1 = (const float*)d_in[3];
  const float* b1 = (const float*)d_in[4];
  const float* W2 = (const float*)d_in[5];
  const float* b2 = (const float*)d_in[6];
  const float* W3 = (const float*)d_in[7];
  const float* b3 = (const float*)d_in[8];
  float* out = (float*)d_out;

  char* ws = (char*)d_ws;
  float* aT  = (float*)(ws + WS_AT);
  float* vT  = (float*)(ws + WS_VT);
  f16*   a16 = (f16*)(ws + WS_A16);
  f16*   v16 = (f16*)(ws + WS_V16);
  f16*   l16 = (f16*)(ws + WS_L16);
  f16*   partials = (f16*)(ws + WS_PART);

  hipLaunchKernelGGL(prep_kernel, dim3(640), dim3(256), 0, stream,
                     l, a, v, aT, vT, a16, v16, l16);
  hipLaunchKernelGGL(fusion_gemm, dim3(256), dim3(1024), 0, stream,
                     W1, aT, vT, a16, v16, l16, partials);
  hipLaunchKernelGGL(tail_kernel, dim3(512), dim3(256), 0, stream,
                     partials, W1, b1, W2, b2, W3, b3, out);
}